// Round 5
// baseline (214.240 us; speedup 1.0000x reference)
//
#include <hip/hip_runtime.h>
#include <hip/hip_bf16.h>

// Problem constants
constexpr int Bc = 2, Sc = 2048, Ec = 1024, Hc = 16, Dc = 64;
constexpr int Mrows = Bc * Sc;   // 4096
constexpr int Kdim  = Ec;        // 1024

// 0.125 (score scale) * log2(e), folded into q at projection time
#define QSCALE 0.18033688011112042f

typedef float  floatx4 __attribute__((ext_vector_type(4)));
typedef short  shortx8 __attribute__((ext_vector_type(8)));

__device__ __forceinline__ unsigned int pack2bf(float a, float b) {
    // round-half-up bf16 pair pack: 2 adds + shift/mask/or (vs ~10 ops for RNE pair)
    union { float f; unsigned int u; } ca, cb;
    ca.f = a; cb.f = b;
    return ((ca.u + 0x8000u) >> 16) | ((cb.u + 0x8000u) & 0xffff0000u);
}
__device__ inline float bf2f(unsigned short u) {
    union { unsigned int i; float f; } c; c.i = ((unsigned int)u) << 16; return c.f;
}
__device__ inline float exp2_fast(float x) {
#if __has_builtin(__builtin_amdgcn_exp2f)
    return __builtin_amdgcn_exp2f(x);
#else
    return __expf(x * 0.69314718056f);
#endif
}

// async global->LDS DMA, 16 B/lane; HW dest = wave-uniform base + lane*16.
__device__ __forceinline__ void gll16(const void* g, void* lds) {
    __builtin_amdgcn_global_load_lds(
        (const __attribute__((address_space(1))) void*)g,
        (__attribute__((address_space(3))) void*)lds, 16, 0, 0);
}

// ---------------------------------------------------------------------------
// Kernel 0: convert x, Wq, Wk, Wv, Wc (fp32) -> bf16 workspace
// ---------------------------------------------------------------------------
__global__ __launch_bounds__(256) void convert_all_kernel(
    const float* __restrict__ x,  const float* __restrict__ Wq,
    const float* __restrict__ Wk, const float* __restrict__ Wv,
    const float* __restrict__ Wc,
    unsigned short* __restrict__ xb,  unsigned short* __restrict__ Wqb,
    unsigned short* __restrict__ Wkb, unsigned short* __restrict__ Wvb,
    unsigned short* __restrict__ Wcb)
{
    const long t = (long)blockIdx.x * 256 + threadIdx.x;
    const long i = t * 4;
    const float* src; unsigned short* dst; long off;
    if (i < 4194304) { src = x; dst = xb; off = i; }
    else {
        long j = i - 4194304;
        int wsel = (int)(j >> 20);
        off = j & 1048575;
        src = (wsel == 0) ? Wq : (wsel == 1) ? Wk : (wsel == 2) ? Wv : Wc;
        dst = (wsel == 0) ? Wqb : (wsel == 1) ? Wkb : (wsel == 2) ? Wvb : Wcb;
    }
    float4 v = *(const float4*)(src + off);
    uint2 u;
    u.x = pack2bf(v.x, v.y);
    u.y = pack2bf(v.z, v.w);
    *(uint2*)(dst + off) = u;
}

// ---------------------------------------------------------------------------
// Kernel 1: MFMA projection + quantum epilogue, 128x128 tile (2 heads/block).
// blockIdx.z selects {q,k,v}. q output is pre-scaled by QSCALE (so attention's
// exp2 input needs no per-element multiply). z==2 writes V^T [B,H,D,S].
// ---------------------------------------------------------------------------
__global__ __launch_bounds__(256) void proj_mfma_kernel(
    const unsigned short* __restrict__ Ab,   // x bf16 [4096,1024]
    const unsigned short* __restrict__ Wqb,
    const unsigned short* __restrict__ Wkb,
    const unsigned short* __restrict__ Wvb,
    unsigned short* __restrict__ oq,         // [B,H,S,D] (pre-scaled)
    unsigned short* __restrict__ ok,         // [B,H,S,D]
    unsigned short* __restrict__ ov)         // [B,H,D,S]
{
    __shared__ __align__(16) char smem[33792];   // As 16K | Ws 16K; Cs overlay
    float (*Cs)[132] = (float(*)[132])smem;
    __shared__ float Sp[64][9];

    const int z = blockIdx.z;
    const unsigned short* Wb = (z == 0) ? Wqb : (z == 1) ? Wkb : Wvb;
    unsigned short* out      = (z == 0) ? oq  : (z == 1) ? ok  : ov;
    const int mode = (z == 2) ? 1 : 0;
    const float osc = (z == 0) ? QSCALE : 1.0f;

    const int tid = threadIdx.x;
    const int lane = tid & 63;
    const int w = tid >> 6, l15 = tid & 15, quad = (tid >> 4) & 3;
    const int wq = w >> 1, wn = w & 1;
    const int m0 = blockIdx.x * 128;
    const int n0 = blockIdx.y * 128;
    const int h0 = n0 >> 6;
    const int sw = l15 & 7;

    floatx4 acc[4][4];
    #pragma unroll
    for (int ms = 0; ms < 4; ++ms)
        #pragma unroll
        for (int ns = 0; ns < 4; ++ns)
            #pragma unroll
            for (int e = 0; e < 4; ++e) acc[ms][ns][e] = 0.0f;

    for (int k0 = 0; k0 < Kdim; k0 += 64) {
        #pragma unroll
        for (int j = 0; j < 4; ++j) {
            int idx = j * 64 + lane;
            int row = 32 * w + (idx >> 3);
            int cg  = ((idx & 7) ^ (idx >> 3)) & 7;
            gll16(Ab + (size_t)(m0 + row) * Kdim + k0 + cg * 8,
                  smem + 4096 * w + 1024 * j);
            gll16(Wb + (size_t)(n0 + row) * Kdim + k0 + cg * 8,
                  smem + 16384 + 4096 * w + 1024 * j);
        }
        __syncthreads();
        #pragma unroll
        for (int ks = 0; ks < 2; ++ks) {
            shortx8 af[4], bf[4];
            #pragma unroll
            for (int ms = 0; ms < 4; ++ms)
                af[ms] = *(shortx8*)(smem + (64 * wq + 16 * ms + l15) * 128
                                     + (((4 * ks + quad) ^ sw) << 4));
            #pragma unroll
            for (int ns = 0; ns < 4; ++ns)
                bf[ns] = *(shortx8*)(smem + 16384 + (64 * wn + 16 * ns + l15) * 128
                                     + (((4 * ks + quad) ^ sw) << 4));
            #pragma unroll
            for (int ms = 0; ms < 4; ++ms)
                #pragma unroll
                for (int ns = 0; ns < 4; ++ns)
                    acc[ms][ns] = __builtin_amdgcn_mfma_f32_16x16x32_bf16(
                        af[ms], bf[ns], acc[ms][ns], 0, 0, 0);
        }
        __syncthreads();
    }

    const int b = m0 >> 11;
    const int sbase = m0 & (Sc - 1);

    for (int pass = 0; pass < 2; ++pass) {
        if (wq == pass) {
            #pragma unroll
            for (int ms = 0; ms < 4; ++ms)
                #pragma unroll
                for (int ns = 0; ns < 4; ++ns)
                    #pragma unroll
                    for (int r = 0; r < 4; ++r)
                        Cs[16 * ms + 4 * quad + r][64 * wn + 16 * ns + l15] =
                            __cosf(acc[ms][ns][r]);
        }
        __syncthreads();
        #pragma unroll
        for (int t = tid; t < 512; t += 256) {
            int row = t >> 3, seg = t & 7;
            float pr = 1.0f;
            #pragma unroll
            for (int c = 0; c < 16; ++c) pr *= Cs[row][seg * 16 + c];
            Sp[row][seg] = pr;
        }
        __syncthreads();
        if (mode == 0) {
            #pragma unroll
            for (int t = tid; t < 512; t += 256) {
                int row = t >> 3, seg = t & 7;
                float p = 1.0f;
                for (int j = (seg & 4); j < seg; ++j) p *= Sp[row][j];
                unsigned int dw[8];
                #pragma unroll
                for (int c2 = 0; c2 < 8; ++c2) {
                    p *= Cs[row][seg * 16 + 2 * c2];     float a = p * osc;
                    p *= Cs[row][seg * 16 + 2 * c2 + 1]; float bb = p * osc;
                    dw[c2] = pack2bf(a, bb);
                }
                int h = h0 + (seg >> 2);
                int s = sbase + pass * 64 + row;
                size_t base = (((size_t)b * Hc + h) * Sc + s) * Dc + (seg & 3) * 16;
                *(uint4*)(out + base)     = *(uint4*)&dw[0];
                *(uint4*)(out + base + 8) = *(uint4*)&dw[4];
            }
            __syncthreads();
        } else {
            #pragma unroll
            for (int t = tid; t < 512; t += 256) {
                int row = t >> 3, seg = t & 7;
                float p = 1.0f;
                for (int j = (seg & 4); j < seg; ++j) p *= Sp[row][j];
                #pragma unroll
                for (int c = 0; c < 16; ++c) { p *= Cs[row][seg * 16 + c]; Cs[row][seg * 16 + c] = p; }
            }
            __syncthreads();
            #pragma unroll
            for (int t = tid; t < 512; t += 256) {
                int col = t >> 2, chunk = t & 3;
                int h = h0 + (col >> 6), d = col & 63;
                unsigned int dw[8];
                #pragma unroll
                for (int j2 = 0; j2 < 8; ++j2)
                    dw[j2] = pack2bf(Cs[chunk * 16 + 2 * j2][col],
                                     Cs[chunk * 16 + 2 * j2 + 1][col]);
                size_t base = (((size_t)b * Hc + h) * Dc + d) * Sc
                              + sbase + pass * 64 + chunk * 16;
                *(uint4*)(out + base)     = *(uint4*)&dw[0];
                *(uint4*)(out + base + 8) = *(uint4*)&dw[4];
            }
            __syncthreads();
        }
    }
}

// ---------------------------------------------------------------------------
// Kernel 2: MFMA flash attention. QTILE=128, fixed-max softmax, S-split x2,
// KTILE=32 with DOUBLE-BUFFERED async DMA staging (next tile issued right
// after the barrier -> the vmcnt(0) barrier drain overlaps with compute).
// Pq is wave-private (64 rows), reused across both q-subtiles.
// LDS: Ks 2x4K + VTs 2x4K + Pq 9.2K = 25.2 KB.
// ---------------------------------------------------------------------------
__global__ __launch_bounds__(256) void attn_mfma_kernel(
    const unsigned short* __restrict__ qg,   // [B,H,S,D] (pre-scaled by QSCALE)
    const unsigned short* __restrict__ kg,   // [B,H,S,D]
    const unsigned short* __restrict__ vtg,  // [B,H,D,S]
    unsigned short* __restrict__ o1,         // partial O, half 0 [B,S,E]
    unsigned short* __restrict__ o2,         // partial O, half 1 [B,S,E]
    float* __restrict__ lpart)               // [2][B*H][S]
{
    __shared__ __align__(16) unsigned short Ks[2][32][64];   // 128B rows, swizzled
    __shared__ __align__(16) unsigned short VTs[2][64][32];  // 64B rows, natural
    __shared__ __align__(16) unsigned short Pq[64][72];      // 144B rows (16B-aligned)

    const int tid  = threadIdx.x;
    const int lane = tid & 63;
    const int w    = tid >> 6;
    const int l15  = tid & 15;
    const int quad = (tid >> 4) & 3;
    const int qb   = blockIdx.x;
    const int half = blockIdx.y;
    const int bh   = blockIdx.z;
    const int sw   = l15 & 7;

    const unsigned short* qp = qg  + (size_t)bh * Sc * Dc;
    const unsigned short* kp = kg  + (size_t)bh * Sc * Dc;
    const unsigned short* vp = vtg + (size_t)bh * Dc * Sc;

    int qrow[2];
    shortx8 qf[2][2];
    #pragma unroll
    for (int qs = 0; qs < 2; ++qs) {
        qrow[qs] = qb * 128 + 32 * w + 16 * qs + l15;
        qf[qs][0] = *(const shortx8*)(qp + (size_t)qrow[qs] * Dc + 8 * quad);
        qf[qs][1] = *(const shortx8*)(qp + (size_t)qrow[qs] * Dc + 32 + 8 * quad);
    }

    floatx4 Oacc[2][4];
    #pragma unroll
    for (int qs = 0; qs < 2; ++qs)
        #pragma unroll
        for (int mt = 0; mt < 4; ++mt)
            #pragma unroll
            for (int e = 0; e < 4; ++e) Oacc[qs][mt][e] = 0.0f;
    float lsum[2] = {0.0f, 0.0f};

    // per-lane global source pointers for the DMA (iter 0)
    const unsigned short* kgl = kp
        + (size_t)(half * 1024 + 8 * w + (lane >> 3)) * Dc
        + (((lane & 7) ^ ((lane >> 3) & 7)) * 8);
    const unsigned short* vgl = vp
        + (size_t)(16 * w + (lane >> 2)) * Sc + half * 1024 + (lane & 3) * 8;

    // prologue: stage tile 0 into buffer 0
    gll16(kgl, &Ks[0][8 * w][0]);
    gll16(vgl, &VTs[0][16 * w][0]);

    for (int it = 0; it < 32; ++it) {
        const int buf = it & 1;
        __syncthreads();   // waits DMA(buf) — issued a full compute-phase ago
        if (it + 1 < 32) {
            const int nb = (it + 1) & 1;
            gll16(kgl + (size_t)(it + 1) * 32 * Dc, &Ks[nb][8 * w][0]);
            gll16(vgl + (it + 1) * 32,              &VTs[nb][16 * w][0]);
        }

        // fragments (shared by both q-subtiles)
        shortx8 kf[2][2], vf[4];
        #pragma unroll
        for (int ks = 0; ks < 2; ++ks)
            #pragma unroll
            for (int mtp = 0; mtp < 2; ++mtp)
                kf[ks][mtp] = *(shortx8*)&Ks[buf][16 * mtp + l15]
                                            [(((4 * ks + quad) ^ sw) & 7) * 8];
        #pragma unroll
        for (int mt = 0; mt < 4; ++mt)
            vf[mt] = *(shortx8*)&VTs[buf][16 * mt + l15][8 * quad];

        #pragma unroll
        for (int qs = 0; qs < 2; ++qs) {
            // ST = K·Q^T : lane holds ST[s=16mtp+4quad+r][q=16w+l15]
            floatx4 st[2];
            #pragma unroll
            for (int mtp = 0; mtp < 2; ++mtp)
                #pragma unroll
                for (int e = 0; e < 4; ++e) st[mtp][e] = 0.0f;
            #pragma unroll
            for (int ks = 0; ks < 2; ++ks)
                #pragma unroll
                for (int mtp = 0; mtp < 2; ++mtp)
                    st[mtp] = __builtin_amdgcn_mfma_f32_16x16x32_bf16(
                        kf[ks][mtp], qf[qs][ks], st[mtp], 0, 0, 0);

            // P = 2^st (q pre-scaled), partial row sums, fast bf16 pack
            float rs = 0.0f;
            #pragma unroll
            for (int mtp = 0; mtp < 2; ++mtp) {
                float p0 = exp2_fast(st[mtp][0]);
                float p1 = exp2_fast(st[mtp][1]);
                float p2 = exp2_fast(st[mtp][2]);
                float p3 = exp2_fast(st[mtp][3]);
                rs += (p0 + p1) + (p2 + p3);
                uint2 u;
                u.x = pack2bf(p0, p1);
                u.y = pack2bf(p2, p3);
                *(uint2*)&Pq[16 * w + l15][16 * mtp + 4 * quad] = u;
            }
            lsum[qs] += rs;

            // O^T += V^T · P^T  (Pq rows wave-private; DS pipe is in-order)
            shortx8 pf = *(shortx8*)&Pq[16 * w + l15][8 * quad];
            #pragma unroll
            for (int mt = 0; mt < 4; ++mt)
                Oacc[qs][mt] = __builtin_amdgcn_mfma_f32_16x16x32_bf16(
                    vf[mt], pf, Oacc[qs][mt], 0, 0, 0);
        }
    }

    // store partial O (bf16, unnormalized) + partial l (fp32)
    const int b = bh >> 4, hh = bh & 15;
    unsigned short* opart = half ? o2 : o1;
    float* lp = lpart + ((size_t)half * (Bc * Hc) + bh) * Sc;
    #pragma unroll
    for (int qs = 0; qs < 2; ++qs) {
        float l = lsum[qs];
        l += __shfl_xor(l, 16, 64);
        l += __shfl_xor(l, 32, 64);
        if (quad == 0) lp[qrow[qs]] = l;
        #pragma unroll
        for (int mt = 0; mt < 4; ++mt) {
            uint2 u;
            u.x = pack2bf(Oacc[qs][mt][0], Oacc[qs][mt][1]);
            u.y = pack2bf(Oacc[qs][mt][2], Oacc[qs][mt][3]);
            size_t base = ((size_t)b * Sc + qrow[qs]) * Ec + hh * 64 + 16 * mt + 4 * quad;
            *(uint2*)(opart + base) = u;
        }
    }
}

// ---------------------------------------------------------------------------
// Kernel 2b: combine halves: att = (O1 + O2) / (l1 + l2), in place into o1.
// ---------------------------------------------------------------------------
__global__ __launch_bounds__(256) void combine_kernel(
    unsigned short* __restrict__ o1,
    const unsigned short* __restrict__ o2,
    const float* __restrict__ lpart)
{
    const size_t t = (size_t)blockIdx.x * 256 + threadIdx.x;
    const size_t base = t * 8;
    const int e = (int)(base & (Ec - 1));
    const int h = e >> 6;
    const size_t bs = base >> 10;
    const int b = (int)(bs >> 11), s = (int)(bs & (Sc - 1));
    const int bh = b * Hc + h;
    const float l = lpart[(size_t)bh * Sc + s]
                  + lpart[(size_t)(Bc * Hc + bh) * Sc + s];
    const float inv = 1.0f / l;
    uint4 a = *(const uint4*)(o1 + base);
    uint4 c = *(const uint4*)(o2 + base);
    const unsigned short* ua = (const unsigned short*)&a;
    const unsigned short* uc = (const unsigned short*)&c;
    unsigned int dw[4];
    #pragma unroll
    for (int i = 0; i < 4; ++i)
        dw[i] = pack2bf((bf2f(ua[2 * i]) + bf2f(uc[2 * i])) * inv,
                        (bf2f(ua[2 * i + 1]) + bf2f(uc[2 * i + 1])) * inv);
    *(uint4*)(o1 + base) = *(uint4*)dw;
}

// ---------------------------------------------------------------------------
// Kernel 3: MFMA out-projection, 64x128 tile, async swizzled staging.
// ---------------------------------------------------------------------------
__global__ __launch_bounds__(256) void outproj_mfma_kernel(
    const unsigned short* __restrict__ Ab,   // attb [4096,1024]
    const unsigned short* __restrict__ Wb,   // Wcb [1024,1024]
    const float* __restrict__ bias,
    float* __restrict__ out)                 // [4096,1024] fp32
{
    __shared__ __align__(16) char smem[24576];   // As 8K | Ws 16K

    const int tid = threadIdx.x;
    const int lane = tid & 63;
    const int w = tid >> 6, l15 = tid & 15, quad = (tid >> 4) & 3;
    const int wq = w >> 1, wn = w & 1;
    const int m0 = blockIdx.x * 64;
    const int n0 = blockIdx.y * 128;
    const int sw = l15 & 7;

    floatx4 acc[2][4];
    #pragma unroll
    for (int ms = 0; ms < 2; ++ms)
        #pragma unroll
        for (int ns = 0; ns < 4; ++ns)
            #pragma unroll
            for (int e = 0; e < 4; ++e) acc[ms][ns][e] = 0.0f;

    for (int k0 = 0; k0 < Kdim; k0 += 64) {
        #pragma unroll
        for (int j = 0; j < 2; ++j) {
            int idx = j * 64 + lane;
            int row = 16 * w + (idx >> 3);
            int cg  = ((idx & 7) ^ (idx >> 3)) & 7;
            gll16(Ab + (size_t)(m0 + row) * Kdim + k0 + cg * 8,
                  smem + 2048 * w + 1024 * j);
        }
        #pragma unroll
        for (int j = 0; j < 4; ++j) {
            int idx = j * 64 + lane;
            int row = 32 * w + (idx >> 3);
            int cg  = ((idx & 7) ^ (idx >> 3)) & 7;
            gll16(Wb + (size_t)(n0 + row) * Kdim + k0 + cg * 8,
                  smem + 8192 + 4096 * w + 1024 * j);
        }
        __syncthreads();
        #pragma unroll
        for (int ks = 0; ks < 2; ++ks) {
            shortx8 af[2], bf[4];
            #pragma unroll
            for (int ms = 0; ms < 2; ++ms)
                af[ms] = *(shortx8*)(smem + (32 * wq + 16 * ms + l15) * 128
                                     + (((4 * ks + quad) ^ sw) << 4));
            #pragma unroll
            for (int ns = 0; ns < 4; ++ns)
                bf[ns] = *(shortx8*)(smem + 8192 + (64 * wn + 16 * ns + l15) * 128
                                     + (((4 * ks + quad) ^ sw) << 4));
            #pragma unroll
            for (int ms = 0; ms < 2; ++ms)
                #pragma unroll
                for (int ns = 0; ns < 4; ++ns)
                    acc[ms][ns] = __builtin_amdgcn_mfma_f32_16x16x32_bf16(
                        af[ms], bf[ns], acc[ms][ns], 0, 0, 0);
        }
        __syncthreads();
    }

    #pragma unroll
    for (int ns = 0; ns < 4; ++ns) {
        const float bv = bias[n0 + 64 * wn + 16 * ns + l15];
        #pragma unroll
        for (int ms = 0; ms < 2; ++ms)
            #pragma unroll
            for (int r = 0; r < 4; ++r) {
                int m = m0 + 32 * wq + 16 * ms + 4 * quad + r;
                out[(size_t)m * Kdim + n0 + 64 * wn + 16 * ns + l15] = acc[ms][ns][r] + bv;
            }
    }
}

// ---------------------------------------------------------------------------
extern "C" void kernel_launch(void* const* d_in, const int* in_sizes, int n_in,
                              void* d_out, int out_size, void* d_ws, size_t ws_size,
                              hipStream_t stream) {
    const float* x  = (const float*)d_in[0];
    const float* Wq = (const float*)d_in[1];
    const float* Wk = (const float*)d_in[2];
    const float* Wv = (const float*)d_in[3];
    const float* Wc = (const float*)d_in[4];
    const float* bc = (const float*)d_in[5];
    float* out = (float*)d_out;

    // ws layout (48 MB): xb 8M | Wqb/Wkb/Wvb/Wcb 2M ea | qb 8M | kb 8M | vtb 8M
    // | attb 8M.  After proj, xb -> O2 partial, Wqb -> lpart; attb = O1.
    char* p = (char*)d_ws;
    unsigned short* xb   = (unsigned short*)(p);
    unsigned short* Wqb  = (unsigned short*)(p + (8u << 20));
    unsigned short* Wkb  = (unsigned short*)(p + (10u << 20));
    unsigned short* Wvb  = (unsigned short*)(p + (12u << 20));
    unsigned short* Wcb  = (unsigned short*)(p + (14u << 20));
    unsigned short* qb_  = (unsigned short*)(p + (16u << 20));
    unsigned short* kb_  = (unsigned short*)(p + (24u << 20));
    unsigned short* vtb  = (unsigned short*)(p + (32u << 20));
    unsigned short* attb = (unsigned short*)(p + (40u << 20));
    unsigned short* o2b  = xb;
    float*          lpart = (float*)(p + (8u << 20));

    hipLaunchKernelGGL(convert_all_kernel, dim3(8192), dim3(256), 0, stream,
                       x, Wq, Wk, Wv, Wc, xb, Wqb, Wkb, Wvb, Wcb);

    hipLaunchKernelGGL(proj_mfma_kernel, dim3(Mrows / 128, Ec / 128, 3), dim3(256), 0, stream,
                       xb, Wqb, Wkb, Wvb, qb_, kb_, vtb);

    hipLaunchKernelGGL(attn_mfma_kernel, dim3(Sc / 128, 2, Bc * Hc), dim3(256), 0, stream,
                       qb_, kb_, vtb, attb, o2b, lpart);

    hipLaunchKernelGGL(combine_kernel, dim3(Mrows * Ec / (256 * 8)), dim3(256), 0, stream,
                       attb, o2b, lpart);

    hipLaunchKernelGGL(outproj_mfma_kernel, dim3(Mrows / 64, Ec / 128), dim3(256), 0, stream,
                       attb, Wcb, bc, out);
}